// Round 6
// baseline (650.207 us; speedup 1.0000x reference)
//
#include <hip/hip_runtime.h>
#include <cstdint>
#include <cstddef>

typedef unsigned short u16;
typedef unsigned int   u32;
typedef unsigned long long u64;
typedef __attribute__((ext_vector_type(8)))  short bf16x8;   // 8 bf16 = 4 VGPRs (MFMA A/B frag)
typedef __attribute__((ext_vector_type(4)))  float f32x4;
typedef __attribute__((ext_vector_type(16))) float f32x16;
typedef __attribute__((ext_vector_type(4)))  unsigned short u16x4;

constexpr int SEQ = 16, DIN = 12288, H1 = 256, H2 = 512, BATCH = 128;

__device__ __forceinline__ u16 f2bf(float x) {
    u32 u = __float_as_uint(x);
    return (u16)((u + 0x7FFFu + ((u >> 16) & 1u)) >> 16);   // round-to-nearest-even
}
__device__ __forceinline__ float fsig(float x) { return 1.f / (1.f + __expf(-x)); }
__device__ __forceinline__ float ftanh(float x) {
    float e = __expf(-2.f * fabsf(x));
    float r = (1.f - e) / (1.f + e);
    return x < 0.f ? -r : r;
}

// ---- fused f32 -> bf16 conversion over 5 segments (one launch) ----
struct CvtDesc {
    const float* src[5];
    u16*         dst[5];
    u32          pfx[6];   // prefix sums in 4-element units
};
__global__ __launch_bounds__(256) void cvt_all(CvtDesc d, int total4) {
    int i = blockIdx.x * 256 + threadIdx.x;
    if (i >= total4) return;
    int s = 0;
#pragma unroll
    for (int k = 1; k < 5; ++k) s += (i >= (int)d.pfx[k]);
    int local = i - (int)d.pfx[s];
    f32x4 v = ((const f32x4*)d.src[s])[local];
    u16x4 o;
#pragma unroll
    for (int q = 0; q < 4; ++q) o[q] = f2bf(v[q]);
    ((u16x4*)d.dst[s])[local] = o;
}

// async 16B global -> LDS (wave-uniform LDS base + lane*16)
__device__ __forceinline__ void async_cp16(const u16* g, u16* l) {
    __builtin_amdgcn_global_load_lds((const __attribute__((address_space(1))) u32*)g,
                                     (__attribute__((address_space(3))) u32*)l, 16, 0, 0);
}

// C[M,N] (f32) = A[M,K] * Bm[N,K]^T. A, Bm bf16 row-major K-contiguous.
// 128x128 tile, BK=32, 4 waves (m97 structure). KSPLIT>1 -> f32 atomic accumulate.
template <int KSPLIT, bool ATOMIC>
__global__ __launch_bounds__(256) void gemm_bt(
    const u16* __restrict__ A, const u16* __restrict__ Bm,
    float* __restrict__ C, int M, int N, int K)
{
    __shared__ u16 As[128 * 32];
    __shared__ u16 Bs[128 * 32];
    const int tid  = threadIdx.x;
    const int lane = tid & 63;
    const int w    = tid >> 6;
    const int wm   = w >> 1, wn = w & 1;
    const int m0 = blockIdx.y * 128, n0 = blockIdx.x * 128;
    const int kchunk = K / KSPLIT;
    const int kbeg = blockIdx.z * kchunk, kend = kbeg + kchunk;
    const int q8 = (lane >> 4) * 8;
    const int wavebase = tid & ~63;

    f32x4 acc[4][4];
    for (int i = 0; i < 4; ++i)
        for (int j = 0; j < 4; ++j) acc[i][j] = f32x4{0.f, 0.f, 0.f, 0.f};

    for (int k0 = kbeg; k0 < kend; k0 += 32) {
        __syncthreads();   // LDS free from previous compute
#pragma unroll
        for (int i = 0; i < 2; ++i) {
            int c = i * 256 + tid;
            async_cp16(A + (size_t)(m0 + (c >> 2)) * K + k0 + (c & 3) * 8,
                       &As[(i * 256 + wavebase) * 8]);
        }
#pragma unroll
        for (int i = 0; i < 2; ++i) {
            int c = i * 256 + tid;
            async_cp16(Bm + (size_t)(n0 + (c >> 2)) * K + k0 + (c & 3) * 8,
                       &Bs[(i * 256 + wavebase) * 8]);
        }
        __syncthreads();   // compiler drains vmcnt before s_barrier
        bf16x8 af[4], bfr[4];
#pragma unroll
        for (int mi = 0; mi < 4; ++mi)
            af[mi] = *(const bf16x8*)&As[(wm * 64 + mi * 16 + (lane & 15)) * 32 + q8];
#pragma unroll
        for (int ni = 0; ni < 4; ++ni)
            bfr[ni] = *(const bf16x8*)&Bs[(wn * 64 + ni * 16 + (lane & 15)) * 32 + q8];
#pragma unroll
        for (int mi = 0; mi < 4; ++mi)
#pragma unroll
            for (int ni = 0; ni < 4; ++ni)
                acc[mi][ni] = __builtin_amdgcn_mfma_f32_16x16x32_bf16(
                    af[mi], bfr[ni], acc[mi][ni], 0, 0, 0);
    }
    // epilogue: C layout col=lane&15, row=(lane>>4)*4+r  [m89-verified]
#pragma unroll
    for (int mi = 0; mi < 4; ++mi)
#pragma unroll
        for (int ni = 0; ni < 4; ++ni) {
            int n = n0 + wn * 64 + ni * 16 + (lane & 15);
            int mbase = m0 + wm * 64 + mi * 16 + (lane >> 4) * 4;
#pragma unroll
            for (int r = 0; r < 4; ++r) {
                size_t idx = (size_t)(mbase + r) * N + n;
                if (ATOMIC) unsafeAtomicAdd(&C[idx], acc[mi][ni][r]);
                else        C[idx] = acc[mi][ni][r];
            }
        }
}

// One cooperative kernel runs all 16 steps of one LSTM layer.
// grid = (BATCH/32, H/32); 4 waves = 4 gates (i,f,g,o).
// Cross-block h exchange via agent-scope atomics + tid0-only directional
// fences: producer does fence(release,agent) [buffer_wbl2] before the counter
// increment; consumer does fence(acquire,agent) [buffer_inv] after the poll.
// This closes the workgroup-fence/agent-scope ordering gap that made R5 race,
// at 2 cache-ops per block per step (vs threadfence's 8).
template <int H>
__global__ __launch_bounds__(256, 1) void lstm_rec(
    const float* __restrict__ pre, const u16* __restrict__ Whh,
    const float* __restrict__ bias, u16* __restrict__ ybf,
    float* __restrict__ yf32, u32* __restrict__ cnt_base)
{
    constexpr int NK = H / 16;
    constexpr int G4 = 4 * H;
    const int tid  = threadIdx.x;
    const int lane = tid & 63;
    const int g    = tid >> 6;          // gate index = wave index
    const int col  = lane & 31;
    const int half = lane >> 5;
    const int b0 = blockIdx.x * 32;
    const int u0 = blockIdx.y * 32;
    const u32 NU = gridDim.y;           // producers per batch-group
    u32* cnt = cnt_base + blockIdx.x * 64;   // 256B-strided counter per b-group

    __shared__ float gbuf[4][1024];     // 32x32 matmul tile per gate

    // B frags: B[k][n] = Whh[g*H + u0 + n][k]; n=col, k=kk*16 + half*8 + j
    bf16x8 bfrag[NK];
    {
        const u16* wrow = Whh + (size_t)(g * H + u0 + col) * H + half * 8;
#pragma unroll
        for (int kk = 0; kk < NK; ++kk) bfrag[kk] = *(const bf16x8*)(wrow + kk * 16);
    }

    const int bl = tid >> 3;            // element phase: thread owns (bl, ul..ul+3)
    const int ul = (tid & 7) * 4;
    f32x4 bia[4];
#pragma unroll
    for (int gg = 0; gg < 4; ++gg)
        bia[gg] = *(const f32x4*)&bias[gg * H + u0 + ul];

    f32x4 c = f32x4{0.f, 0.f, 0.f, 0.f};

    for (int t = 0; t < SEQ; ++t) {
        // pre loads first: independent of h, in flight during the poll
        const float* prow = pre + (size_t)(t * BATCH + b0 + bl) * G4 + u0 + ul;
        f32x4 xi = *(const f32x4*)(prow);
        f32x4 xf = *(const f32x4*)(prow + H);
        f32x4 xg = *(const f32x4*)(prow + 2 * H);
        f32x4 xo = *(const f32x4*)(prow + 3 * H);

        f32x16 acc, acc2;
#pragma unroll
        for (int r = 0; r < 16; ++r) { acc[r] = 0.f; acc2[r] = 0.f; }
        if (t > 0) {
            // wait for all NU producers of this b-group to finish step t-1
            if (tid == 0) {
                const u32 target = NU * (u32)t;
                while (__hip_atomic_load(cnt, __ATOMIC_RELAXED,
                                         __HIP_MEMORY_SCOPE_AGENT) < target)
                    __builtin_amdgcn_s_sleep(1);
                // acquire: invalidate any stale cached copies before h loads
                __builtin_amdgcn_fence(__ATOMIC_ACQUIRE, "agent");
            }
            __syncthreads();
            // hoist ALL h loads (agent-scope, LLC): one latency, fully pipelined
            u64* yq = (u64*)(ybf + (size_t)((t - 1) * BATCH + b0 + col) * H);
            u64 hq0[NK], hq1[NK];
#pragma unroll
            for (int kk = 0; kk < NK; ++kk) {
                hq0[kk] = __hip_atomic_load(yq + kk * 4 + half * 2,
                                            __ATOMIC_RELAXED, __HIP_MEMORY_SCOPE_AGENT);
                hq1[kk] = __hip_atomic_load(yq + kk * 4 + half * 2 + 1,
                                            __ATOMIC_RELAXED, __HIP_MEMORY_SCOPE_AGENT);
            }
            // two independent accumulator chains (even/odd kk)
#pragma unroll
            for (int kk = 0; kk < NK; kk += 2) {
                union { u64 q[2]; bf16x8 v; } u;
                u.q[0] = hq0[kk]; u.q[1] = hq1[kk];
                acc = __builtin_amdgcn_mfma_f32_32x32x16_bf16(u.v, bfrag[kk], acc, 0, 0, 0);
                union { u64 q[2]; bf16x8 v; } w2;
                w2.q[0] = hq0[kk + 1]; w2.q[1] = hq1[kk + 1];
                acc2 = __builtin_amdgcn_mfma_f32_32x32x16_bf16(w2.v, bfrag[kk + 1], acc2, 0, 0, 0);
            }
        }
        // C layout: col(n)=lane&31, row(m)=(r&3)+8*(r>>2)+4*half  [m74/m101-verified]
#pragma unroll
        for (int r = 0; r < 16; ++r) {
            int row = (r & 3) + 8 * (r >> 2) + 4 * half;
            gbuf[g][row * 32 + col] = acc[r] + acc2[r];
        }
        __syncthreads();

        f32x4 mi = *(const f32x4*)&gbuf[0][tid * 4];
        f32x4 mf = *(const f32x4*)&gbuf[1][tid * 4];
        f32x4 mg = *(const f32x4*)&gbuf[2][tid * 4];
        f32x4 mo = *(const f32x4*)&gbuf[3][tid * 4];

        u16x4 hb;
        f32x4 hf;
#pragma unroll
        for (int q = 0; q < 4; ++q) {
            float iv = fsig(xi[q] + mi[q] + bia[0][q]);
            float fv = fsig(xf[q] + mf[q] + bia[1][q]);
            float gv = ftanh(xg[q] + mg[q] + bia[2][q]);
            float ov = fsig(xo[q] + mo[q] + bia[3][q]);
            float cq = fv * c[q] + iv * gv;
            c[q] = cq;
            float hv = ov * ftanh(cq);
            hf[q] = hv;
            hb[q] = f2bf(hv);
        }
        size_t oidx = (size_t)(t * BATCH + b0 + bl) * H + u0 + ul;
        {   // h store via agent-scope atomic store (8B, lands at LLC)
            union { u16x4 v; u64 q; } hu; hu.v = hb;
            __hip_atomic_store((u64*)(ybf + oidx), hu.q,
                               __ATOMIC_RELAXED, __HIP_MEMORY_SCOPE_AGENT);
        }
        if (yf32) *(f32x4*)(yf32 + oidx) = hf;

        __syncthreads();   // all waves drain vmcnt(0) before barrier exit
        if (t < SEQ - 1 && tid == 0) {
            // release: push any dirty lines to LLC before signaling
            __builtin_amdgcn_fence(__ATOMIC_RELEASE, "agent");
            __hip_atomic_fetch_add(cnt, 1u, __ATOMIC_RELAXED, __HIP_MEMORY_SCOPE_AGENT);
        }
    }
}

extern "C" void kernel_launch(void* const* d_in, const int* in_sizes, int n_in,
                              void* d_out, int out_size, void* d_ws, size_t ws_size,
                              hipStream_t stream) {
    const float* inp  = (const float*)d_in[0];   // [B,T,IN] flat == [T*B, IN] rows (t*B+b)
    const float* Wih1 = (const float*)d_in[1];
    const float* Whh1 = (const float*)d_in[2];
    const float* b1   = (const float*)d_in[3];
    const float* Wih2 = (const float*)d_in[4];
    const float* Whh2 = (const float*)d_in[5];
    const float* b2   = (const float*)d_in[6];
    float* out = (float*)d_out;                  // [T,B,H2] flat == y2.reshape(B,-1)

    const int M = SEQ * BATCH;                   // 2048
    constexpr size_t NX   = (size_t)SEQ * BATCH * DIN;     // 25,165,824
    constexpr size_t NW1  = (size_t)4 * H1 * DIN;          // 12,582,912
    constexpr size_t NWH1 = (size_t)4 * H1 * H1;           //    262,144
    constexpr size_t NW2  = (size_t)4 * H2 * H1;           //    524,288
    constexpr size_t NWH2 = (size_t)4 * H2 * H2;           //  1,048,576

    char* ws = (char*)d_ws;
    u16* xb    = (u16*)ws;                         ws += NX   * 2;   // 50.3 MB
    u16* W1b   = (u16*)ws;                         ws += NW1  * 2;   // 25.2 MB
    u16* Whh1b = (u16*)ws;                         ws += NWH1 * 2;   //  0.5 MB
    u16* W2b   = (u16*)ws;                         ws += NW2  * 2;   //  1.0 MB
    u16* Whh2b = (u16*)ws;                         ws += NWH2 * 2;   //  2.1 MB
    float* pre1 = (float*)ws;                      ws += (size_t)M * 4 * H1 * 4;  // 8.4 MB
    float* pre2 = (float*)ws;                      ws += (size_t)M * 4 * H2 * 4;  // 16.8 MB
    u16* y1  = (u16*)ws;                           ws += (size_t)M * H1 * 2;      // 1.0 MB
    u16* y2b = (u16*)ws;                           ws += (size_t)M * H2 * 2;      // 2.1 MB
    u32* bar1 = (u32*)ws;                          // 4 counters, 256B stride
    u32* bar2 = (u32*)(ws + 1024);                 // 4 counters, 256B stride

    // fused f32 -> bf16 conversions (one launch)
    {
        CvtDesc d;
        d.src[0] = inp;  d.dst[0] = xb;
        d.src[1] = Wih1; d.dst[1] = W1b;
        d.src[2] = Whh1; d.dst[2] = Whh1b;
        d.src[3] = Wih2; d.dst[3] = W2b;
        d.src[4] = Whh2; d.dst[4] = Whh2b;
        u32 sz4[5] = {NX / 4, NW1 / 4, NWH1 / 4, NW2 / 4, NWH2 / 4};
        d.pfx[0] = 0;
        for (int k = 0; k < 5; ++k) d.pfx[k + 1] = d.pfx[k] + sz4[k];
        int total4 = (int)d.pfx[5];
        cvt_all<<<(total4 + 255) / 256, 256, 0, stream>>>(d, total4);
    }

    // zero sync counters (ws is re-poisoned 0xAA before every call)
    hipMemsetAsync(bar1, 0, 2048, stream);

    // pre1 = x @ Wih1^T (6-way K-split -> 768 blocks = 3/CU; b1 folded into rec1)
    hipMemsetAsync(pre1, 0, (size_t)M * 4 * H1 * sizeof(float), stream);
    gemm_bt<6, true><<<dim3(4 * H1 / 128, M / 128, 6), 256, 0, stream>>>(
        xb, W1b, pre1, M, 4 * H1, DIN);

    {   // layer-1 recurrence (cooperative, 32 blocks)
        float* nul = nullptr;
        void* a[6] = {(void*)&pre1, (void*)&Whh1b, (void*)&b1, (void*)&y1,
                      (void*)&nul, (void*)&bar1};
        hipLaunchCooperativeKernel(lstm_rec<H1>, dim3(BATCH / 32, H1 / 32), dim3(256),
                                   a, 0, stream);
    }

    // pre2 = y1 @ Wih2^T (b2 folded into rec2)
    gemm_bt<1, false><<<dim3(4 * H2 / 128, M / 128, 1), 256, 0, stream>>>(
        y1, W2b, pre2, M, 4 * H2, H1);

    {   // layer-2 recurrence (cooperative, 64 blocks) -> d_out (f32) + y2b (bf16 recurrent)
        void* a[6] = {(void*)&pre2, (void*)&Whh2b, (void*)&b2, (void*)&y2b,
                      (void*)&out, (void*)&bar2};
        hipLaunchCooperativeKernel(lstm_rec<H2>, dim3(BATCH / 32, H2 / 32), dim3(256),
                                   a, 0, stream);
    }
}

// Round 7
// 597.354 us; speedup vs baseline: 1.0885x; 1.0885x over previous
//
#include <hip/hip_runtime.h>
#include <cstdint>
#include <cstddef>

typedef unsigned short u16;
typedef unsigned int   u32;
typedef unsigned long long u64;
typedef __attribute__((ext_vector_type(8)))  short bf16x8;   // 8 bf16 = 4 VGPRs (MFMA A/B frag)
typedef __attribute__((ext_vector_type(4)))  float f32x4;
typedef __attribute__((ext_vector_type(16))) float f32x16;
typedef __attribute__((ext_vector_type(4)))  unsigned short u16x4;

constexpr int SEQ = 16, DIN = 12288, H1 = 256, H2 = 512, BATCH = 128;

__device__ __forceinline__ u16 f2bf(float x) {
    u32 u = __float_as_uint(x);
    return (u16)((u + 0x7FFFu + ((u >> 16) & 1u)) >> 16);   // round-to-nearest-even
}
__device__ __forceinline__ float fsig(float x) { return 1.f / (1.f + __expf(-x)); }
__device__ __forceinline__ float ftanh(float x) {
    float e = __expf(-2.f * fabsf(x));
    float r = (1.f - e) / (1.f + e);
    return x < 0.f ? -r : r;
}

// ---- fused f32 -> bf16 conversion over 5 segments (one launch) ----
struct CvtDesc {
    const float* src[5];
    u16*         dst[5];
    u32          pfx[6];   // prefix sums in 4-element units
};
__global__ __launch_bounds__(256) void cvt_all(CvtDesc d, int total4) {
    int i = blockIdx.x * 256 + threadIdx.x;
    if (i >= total4) return;
    int s = 0;
#pragma unroll
    for (int k = 1; k < 5; ++k) s += (i >= (int)d.pfx[k]);
    int local = i - (int)d.pfx[s];
    f32x4 v = ((const f32x4*)d.src[s])[local];
    u16x4 o;
#pragma unroll
    for (int q = 0; q < 4; ++q) o[q] = f2bf(v[q]);
    ((u16x4*)d.dst[s])[local] = o;
}

// async 16B global -> LDS (wave-uniform LDS base + lane*16)
__device__ __forceinline__ void async_cp16(const u16* g, u16* l) {
    __builtin_amdgcn_global_load_lds((const __attribute__((address_space(1))) u32*)g,
                                     (__attribute__((address_space(3))) u32*)l, 16, 0, 0);
}

// C[M,N] (f32) = A[M,K] * Bm[N,K]^T. A, Bm bf16 row-major K-contiguous.
// 128x128 tile, BK=32, 4 waves (m97 structure). KSPLIT>1 -> f32 atomic accumulate.
template <int KSPLIT, bool ATOMIC>
__global__ __launch_bounds__(256) void gemm_bt(
    const u16* __restrict__ A, const u16* __restrict__ Bm,
    float* __restrict__ C, int M, int N, int K)
{
    __shared__ u16 As[128 * 32];
    __shared__ u16 Bs[128 * 32];
    const int tid  = threadIdx.x;
    const int lane = tid & 63;
    const int w    = tid >> 6;
    const int wm   = w >> 1, wn = w & 1;
    const int m0 = blockIdx.y * 128, n0 = blockIdx.x * 128;
    const int kchunk = K / KSPLIT;
    const int kbeg = blockIdx.z * kchunk, kend = kbeg + kchunk;
    const int q8 = (lane >> 4) * 8;
    const int wavebase = tid & ~63;

    f32x4 acc[4][4];
    for (int i = 0; i < 4; ++i)
        for (int j = 0; j < 4; ++j) acc[i][j] = f32x4{0.f, 0.f, 0.f, 0.f};

    for (int k0 = kbeg; k0 < kend; k0 += 32) {
        __syncthreads();   // LDS free from previous compute
#pragma unroll
        for (int i = 0; i < 2; ++i) {
            int c = i * 256 + tid;
            async_cp16(A + (size_t)(m0 + (c >> 2)) * K + k0 + (c & 3) * 8,
                       &As[(i * 256 + wavebase) * 8]);
        }
#pragma unroll
        for (int i = 0; i < 2; ++i) {
            int c = i * 256 + tid;
            async_cp16(Bm + (size_t)(n0 + (c >> 2)) * K + k0 + (c & 3) * 8,
                       &Bs[(i * 256 + wavebase) * 8]);
        }
        __syncthreads();   // compiler drains vmcnt before s_barrier
        bf16x8 af[4], bfr[4];
#pragma unroll
        for (int mi = 0; mi < 4; ++mi)
            af[mi] = *(const bf16x8*)&As[(wm * 64 + mi * 16 + (lane & 15)) * 32 + q8];
#pragma unroll
        for (int ni = 0; ni < 4; ++ni)
            bfr[ni] = *(const bf16x8*)&Bs[(wn * 64 + ni * 16 + (lane & 15)) * 32 + q8];
#pragma unroll
        for (int mi = 0; mi < 4; ++mi)
#pragma unroll
            for (int ni = 0; ni < 4; ++ni)
                acc[mi][ni] = __builtin_amdgcn_mfma_f32_16x16x32_bf16(
                    af[mi], bfr[ni], acc[mi][ni], 0, 0, 0);
    }
    // epilogue: C layout col=lane&15, row=(lane>>4)*4+r  [m89-verified]
#pragma unroll
    for (int mi = 0; mi < 4; ++mi)
#pragma unroll
        for (int ni = 0; ni < 4; ++ni) {
            int n = n0 + wn * 64 + ni * 16 + (lane & 15);
            int mbase = m0 + wm * 64 + mi * 16 + (lane >> 4) * 4;
#pragma unroll
            for (int r = 0; r < 4; ++r) {
                size_t idx = (size_t)(mbase + r) * N + n;
                if (ATOMIC) unsafeAtomicAdd(&C[idx], acc[mi][ni][r]);
                else        C[idx] = acc[mi][ni][r];
            }
        }
}

// One cooperative kernel runs all 16 steps of one LSTM layer.
// grid = (BATCH/32, H/32); 4 waves = 4 gates (i,f,g,o).
// Sync protocol (fence-free):
//  - h stores are agent-scope atomic EXCHANGES: RMWs execute at the LLC, so
//    their vmcnt ack (drained by __syncthreads) means the data IS at the
//    coherence point — no buffer_wbl2 needed.
//  - per-producer FLAGS (256B-strided): producer tid0 stores flag=t+1 after
//    the drain; consumer wave-0 lanes <NU each poll one flag (exec-mask loop
//    = wait-for-all). No shared-counter RMW serialization, no poll contention.
//  - consumer h loads are agent-scope atomics (read at LLC, bypass L1/L2).
template <int H>
__global__ __launch_bounds__(256, 1) void lstm_rec(
    const float* __restrict__ pre, const u16* __restrict__ Whh,
    const float* __restrict__ bias, u16* __restrict__ ybf,
    float* __restrict__ yf32, u32* __restrict__ flag_base)
{
    constexpr int NK = H / 16;
    constexpr int G4 = 4 * H;
    const int tid  = threadIdx.x;
    const int lane = tid & 63;
    const int g    = tid >> 6;          // gate index = wave index
    const int col  = lane & 31;
    const int half = lane >> 5;
    const int b0 = blockIdx.x * 32;
    const int u0 = blockIdx.y * 32;
    const u32 NU = gridDim.y;           // producers per batch-group
    u32* flags  = flag_base + blockIdx.x * (16 * 64);   // this b-group's flag slots
    u32* myflag = flags + blockIdx.y * 64;              // 256B-strided

    __shared__ float gbuf[4][1024];     // 32x32 matmul tile per gate

    // B frags: B[k][n] = Whh[g*H + u0 + n][k]; n=col, k=kk*16 + half*8 + j
    bf16x8 bfrag[NK];
    {
        const u16* wrow = Whh + (size_t)(g * H + u0 + col) * H + half * 8;
#pragma unroll
        for (int kk = 0; kk < NK; ++kk) bfrag[kk] = *(const bf16x8*)(wrow + kk * 16);
    }

    const int bl = tid >> 3;            // element phase: thread owns (bl, ul..ul+3)
    const int ul = (tid & 7) * 4;
    f32x4 bia[4];
#pragma unroll
    for (int gg = 0; gg < 4; ++gg)
        bia[gg] = *(const f32x4*)&bias[gg * H + u0 + ul];

    f32x4 c = f32x4{0.f, 0.f, 0.f, 0.f};

    for (int t = 0; t < SEQ; ++t) {
        // pre loads first: independent of h, in flight during the poll
        const float* prow = pre + (size_t)(t * BATCH + b0 + bl) * G4 + u0 + ul;
        f32x4 xi = *(const f32x4*)(prow);
        f32x4 xf = *(const f32x4*)(prow + H);
        f32x4 xg = *(const f32x4*)(prow + 2 * H);
        f32x4 xo = *(const f32x4*)(prow + 3 * H);

        f32x16 acc, acc2;
#pragma unroll
        for (int r = 0; r < 16; ++r) { acc[r] = 0.f; acc2[r] = 0.f; }
        if (t > 0) {
            // wave 0, lanes <NU: each polls one producer's flag; the wave's
            // exec-mask loop exits only when ALL lanes see flag >= t.
            if (g == 0 && lane < (int)NU) {
                while (__hip_atomic_load(flags + lane * 64, __ATOMIC_RELAXED,
                                         __HIP_MEMORY_SCOPE_AGENT) < (u32)t)
                    __builtin_amdgcn_s_sleep(1);
            }
            __syncthreads();
            // hoist ALL h loads (agent-scope, LLC): one latency, fully pipelined
            u64* yq = (u64*)(ybf + (size_t)((t - 1) * BATCH + b0 + col) * H);
            u64 hq0[NK], hq1[NK];
#pragma unroll
            for (int kk = 0; kk < NK; ++kk) {
                hq0[kk] = __hip_atomic_load(yq + kk * 4 + half * 2,
                                            __ATOMIC_RELAXED, __HIP_MEMORY_SCOPE_AGENT);
                hq1[kk] = __hip_atomic_load(yq + kk * 4 + half * 2 + 1,
                                            __ATOMIC_RELAXED, __HIP_MEMORY_SCOPE_AGENT);
            }
            // two independent accumulator chains (even/odd kk)
#pragma unroll
            for (int kk = 0; kk < NK; kk += 2) {
                union { u64 q[2]; bf16x8 v; } u;
                u.q[0] = hq0[kk]; u.q[1] = hq1[kk];
                acc = __builtin_amdgcn_mfma_f32_32x32x16_bf16(u.v, bfrag[kk], acc, 0, 0, 0);
                union { u64 q[2]; bf16x8 v; } w2;
                w2.q[0] = hq0[kk + 1]; w2.q[1] = hq1[kk + 1];
                acc2 = __builtin_amdgcn_mfma_f32_32x32x16_bf16(w2.v, bfrag[kk + 1], acc2, 0, 0, 0);
            }
        }
        // C layout: col(n)=lane&31, row(m)=(r&3)+8*(r>>2)+4*half  [m74/m101-verified]
#pragma unroll
        for (int r = 0; r < 16; ++r) {
            int row = (r & 3) + 8 * (r >> 2) + 4 * half;
            gbuf[g][row * 32 + col] = acc[r] + acc2[r];
        }
        __syncthreads();

        f32x4 mi = *(const f32x4*)&gbuf[0][tid * 4];
        f32x4 mf = *(const f32x4*)&gbuf[1][tid * 4];
        f32x4 mg = *(const f32x4*)&gbuf[2][tid * 4];
        f32x4 mo = *(const f32x4*)&gbuf[3][tid * 4];

        u16x4 hb;
        f32x4 hf;
#pragma unroll
        for (int q = 0; q < 4; ++q) {
            float iv = fsig(xi[q] + mi[q] + bia[0][q]);
            float fv = fsig(xf[q] + mf[q] + bia[1][q]);
            float gv = ftanh(xg[q] + mg[q] + bia[2][q]);
            float ov = fsig(xo[q] + mo[q] + bia[3][q]);
            float cq = fv * c[q] + iv * gv;
            c[q] = cq;
            float hv = ov * ftanh(cq);
            hf[q] = hv;
            hb[q] = f2bf(hv);
        }
        size_t oidx = (size_t)(t * BATCH + b0 + bl) * H + u0 + ul;
        {   // h store as agent-scope atomic EXCHANGE: lands AT the LLC before ack
            union { u16x4 v; u64 q; } hu; hu.v = hb;
            (void)__hip_atomic_exchange((u64*)(ybf + oidx), hu.q,
                                        __ATOMIC_RELAXED, __HIP_MEMORY_SCOPE_AGENT);
        }
        if (yf32) *(f32x4*)(yf32 + oidx) = hf;

        __syncthreads();   // every wave drains vmcnt(0): all h xchgs acked at LLC
        if (t < SEQ - 1 && tid == 0)
            __hip_atomic_store(myflag, (u32)(t + 1),
                               __ATOMIC_RELAXED, __HIP_MEMORY_SCOPE_AGENT);
    }
}

extern "C" void kernel_launch(void* const* d_in, const int* in_sizes, int n_in,
                              void* d_out, int out_size, void* d_ws, size_t ws_size,
                              hipStream_t stream) {
    const float* inp  = (const float*)d_in[0];   // [B,T,IN] flat == [T*B, IN] rows (t*B+b)
    const float* Wih1 = (const float*)d_in[1];
    const float* Whh1 = (const float*)d_in[2];
    const float* b1   = (const float*)d_in[3];
    const float* Wih2 = (const float*)d_in[4];
    const float* Whh2 = (const float*)d_in[5];
    const float* b2   = (const float*)d_in[6];
    float* out = (float*)d_out;                  // [T,B,H2] flat == y2.reshape(B,-1)

    const int M = SEQ * BATCH;                   // 2048
    constexpr size_t NX   = (size_t)SEQ * BATCH * DIN;     // 25,165,824
    constexpr size_t NW1  = (size_t)4 * H1 * DIN;          // 12,582,912
    constexpr size_t NWH1 = (size_t)4 * H1 * H1;           //    262,144
    constexpr size_t NW2  = (size_t)4 * H2 * H1;           //    524,288
    constexpr size_t NWH2 = (size_t)4 * H2 * H2;           //  1,048,576

    char* ws = (char*)d_ws;
    u16* xb    = (u16*)ws;                         ws += NX   * 2;   // 50.3 MB
    u16* W1b   = (u16*)ws;                         ws += NW1  * 2;   // 25.2 MB
    u16* Whh1b = (u16*)ws;                         ws += NWH1 * 2;   //  0.5 MB
    u16* W2b   = (u16*)ws;                         ws += NW2  * 2;   //  1.0 MB
    u16* Whh2b = (u16*)ws;                         ws += NWH2 * 2;   //  2.1 MB
    float* pre1 = (float*)ws;                      ws += (size_t)M * 4 * H1 * 4;  // 8.4 MB
    float* pre2 = (float*)ws;                      ws += (size_t)M * 4 * H2 * 4;  // 16.8 MB
    u16* y1  = (u16*)ws;                           ws += (size_t)M * H1 * 2;      // 1.0 MB
    u16* y2b = (u16*)ws;                           ws += (size_t)M * H2 * 2;      // 2.1 MB
    u32* flg1 = (u32*)ws;                          // [4 bgroups][16 slots][64 u32]
    u32* flg2 = (u32*)(ws + 16384);                // same layout

    // fused f32 -> bf16 conversions (one launch)
    {
        CvtDesc d;
        d.src[0] = inp;  d.dst[0] = xb;
        d.src[1] = Wih1; d.dst[1] = W1b;
        d.src[2] = Whh1; d.dst[2] = Whh1b;
        d.src[3] = Wih2; d.dst[3] = W2b;
        d.src[4] = Whh2; d.dst[4] = Whh2b;
        u32 sz4[5] = {NX / 4, NW1 / 4, NWH1 / 4, NW2 / 4, NWH2 / 4};
        d.pfx[0] = 0;
        for (int k = 0; k < 5; ++k) d.pfx[k + 1] = d.pfx[k] + sz4[k];
        int total4 = (int)d.pfx[5];
        cvt_all<<<(total4 + 255) / 256, 256, 0, stream>>>(d, total4);
    }

    // zero sync flags (ws is re-poisoned 0xAA before every call)
    hipMemsetAsync(flg1, 0, 32768, stream);

    // pre1 = x @ Wih1^T (6-way K-split -> 768 blocks = 3/CU; b1 folded into rec1)
    hipMemsetAsync(pre1, 0, (size_t)M * 4 * H1 * sizeof(float), stream);
    gemm_bt<6, true><<<dim3(4 * H1 / 128, M / 128, 6), 256, 0, stream>>>(
        xb, W1b, pre1, M, 4 * H1, DIN);

    {   // layer-1 recurrence (cooperative, 32 blocks)
        float* nul = nullptr;
        void* a[6] = {(void*)&pre1, (void*)&Whh1b, (void*)&b1, (void*)&y1,
                      (void*)&nul, (void*)&flg1};
        hipLaunchCooperativeKernel(lstm_rec<H1>, dim3(BATCH / 32, H1 / 32), dim3(256),
                                   a, 0, stream);
    }

    // pre2 = y1 @ Wih2^T (b2 folded into rec2)
    gemm_bt<1, false><<<dim3(4 * H2 / 128, M / 128, 1), 256, 0, stream>>>(
        y1, W2b, pre2, M, 4 * H2, H1);

    {   // layer-2 recurrence (cooperative, 64 blocks) -> d_out (f32) + y2b (bf16 recurrent)
        void* a[6] = {(void*)&pre2, (void*)&Whh2b, (void*)&b2, (void*)&y2b,
                      (void*)&out, (void*)&flg2};
        hipLaunchCooperativeKernel(lstm_rec<H2>, dim3(BATCH / 32, H2 / 32), dim3(256),
                                   a, 0, stream);
    }
}